// Round 1
// baseline (1392.295 us; speedup 1.0000x reference)
//
#include <hip/hip_runtime.h>

// SelfCorrelationPercPooling: x (32,32,32,512) f32 ->
//   corr[b] = X·Xᵀ/512 (1024x1024), per-row descending sort, gather 256 ranks.
// Fused single kernel: one workgroup = (batch, 16-row block).
//   Phase 1: fp32 GEMM, A-tile in LDS (broadcast reads), B gathered from L2.
//   Phase 2: hybrid bitonic sort of 16 rows x 1024 in LDS:
//            strides<=16 in registers (32-elem chunks), strides>=32 as float4 LDS CEs.
//   Phase 3: gather ranks[p] = rint(1 + p*1022/255), coalesced store.

#define NMAPS 1024
#define FDIM 512
#define NPOOL 256
#define TM 16
#define NT 256

// XOR swizzle on float4 index within a 1024-float row: breaks the 128B-stride
// bank-conflict pattern for the 32-float chunk loads (all accesses go through this).
__device__ __forceinline__ int sw4(int row, int c4) {
  return (row << 8) | (c4 ^ ((c4 >> 3) & 7));
}

__device__ __forceinline__ void ce(float& a, float& b, bool desc) {
  float mn = fminf(a, b);
  float mx = fmaxf(a, b);
  a = desc ? mx : mn;
  b = desc ? mn : mx;
}

__global__ __launch_bounds__(NT) void selfcorr_pool_kernel(const float* __restrict__ x,
                                                           float* __restrict__ out) {
  __shared__ float lds[TM * NMAPS];  // 64 KB: A-tile first, then score rows S
  float4* S4 = reinterpret_cast<float4*>(lds);
  const int tid = threadIdx.x;
  const int b = blockIdx.y;
  const int m0 = blockIdx.x * TM;
  const float4* Xb = reinterpret_cast<const float4*>(x) + (size_t)b * NMAPS * (FDIM / 4);

  // ---- A tile: 16 rows x 512 f32, coalesced float4 loads ----
  float4* A4 = reinterpret_cast<float4*>(lds);  // A4[m*128 + k4]
#pragma unroll
  for (int idx = tid; idx < TM * (FDIM / 4); idx += NT) {
    A4[idx] = Xb[(m0 + (idx >> 7)) * 128 + (idx & 127)];
  }
  __syncthreads();

  // ---- GEMM: acc[m][j] = dot(x[b][m0+m], x[b][tid + 256j]) ----
  float acc[TM][4];
#pragma unroll
  for (int m = 0; m < TM; ++m)
#pragma unroll
    for (int j = 0; j < 4; ++j) acc[m][j] = 0.0f;

  float4 nb0 = Xb[(tid + 0) * 128];
  float4 nb1 = Xb[(tid + 256) * 128];
  float4 nb2 = Xb[(tid + 512) * 128];
  float4 nb3 = Xb[(tid + 768) * 128];
  for (int k4 = 0; k4 < 128; ++k4) {
    float4 b0 = nb0, b1 = nb1, b2 = nb2, b3 = nb3;
    const int kn = (k4 < 127) ? (k4 + 1) : 127;  // prefetch next k (clamped, in-bounds)
    nb0 = Xb[(tid + 0) * 128 + kn];
    nb1 = Xb[(tid + 256) * 128 + kn];
    nb2 = Xb[(tid + 512) * 128 + kn];
    nb3 = Xb[(tid + 768) * 128 + kn];
#pragma unroll
    for (int m = 0; m < TM; ++m) {
      float4 a = A4[m * 128 + k4];  // wave-uniform address -> LDS broadcast
      acc[m][0] += a.x * b0.x + a.y * b0.y + a.z * b0.z + a.w * b0.w;
      acc[m][1] += a.x * b1.x + a.y * b1.y + a.z * b1.z + a.w * b1.w;
      acc[m][2] += a.x * b2.x + a.y * b2.y + a.z * b2.z + a.w * b2.w;
      acc[m][3] += a.x * b3.x + a.y * b3.y + a.z * b3.z + a.w * b3.w;
    }
  }
  __syncthreads();  // A-tile now dead; LDS becomes S

  // ---- write S (swizzled), scaled by 1/F ----
#pragma unroll
  for (int m = 0; m < TM; ++m) {
#pragma unroll
    for (int j = 0; j < 4; ++j) {
      const int n = tid + (j << 8);
      lds[sw4(m, n >> 2) * 4 + (n & 3)] = acc[m][j] * (1.0f / FDIM);
    }
  }
  __syncthreads();

  // ---- sort phase 1: each thread fully sorts two 32-chunks in registers.
  //      chunk at base col c*32 sorted DESC iff (base & 32)==0 (alternating). ----
#pragma unroll
  for (int c = 0; c < 2; ++c) {
    const int cid = tid + (c << 8);
    const int row = cid >> 5;
    const int chunk = cid & 31;
    float r[32];
#pragma unroll
    for (int q = 0; q < 8; ++q) {
      float4 t = S4[sw4(row, (chunk << 3) + q)];
      r[q * 4 + 0] = t.x; r[q * 4 + 1] = t.y; r[q * 4 + 2] = t.z; r[q * 4 + 3] = t.w;
    }
    const bool D = ((chunk & 1) == 0);
#pragma unroll
    for (int k2 = 2; k2 <= 32; k2 <<= 1) {
#pragma unroll
      for (int j = k2 >> 1; j > 0; j >>= 1) {
#pragma unroll
        for (int i = 0; i < 32; ++i) {
          if ((i & j) == 0) ce(r[i], r[i | j], ((i & k2) == 0) ? D : !D);
        }
      }
    }
#pragma unroll
    for (int q = 0; q < 8; ++q) {
      S4[sw4(row, (chunk << 3) + q)] =
          make_float4(r[q * 4 + 0], r[q * 4 + 1], r[q * 4 + 2], r[q * 4 + 3]);
    }
  }
  __syncthreads();

  // ---- sort phase 2: merges k = 64..1024.
  //      strides j>=32: float4-vectorized LDS compare-exchanges.
  //      strides j<=16: register pass on 32-chunks (uniform direction per chunk). ----
  for (int k = 64; k <= NMAPS; k <<= 1) {
    for (int j = k >> 1; j >= 32; j >>= 1) {
      const int j4 = j >> 2;
      const int kq = k >> 2;
#pragma unroll
      for (int q = 0; q < 8; ++q) {
        const int g = tid + (q << 8);       // 2048 vec-CEs per level
        const int row = g >> 7;
        const int v = g & 127;
        const int i4 = ((v & ~(j4 - 1)) << 1) | (v & (j4 - 1));
        const bool desc = ((i4 & kq) == 0);
        const int ia = sw4(row, i4);
        const int ib = sw4(row, i4 + j4);
        float4 va = S4[ia];
        float4 vb = S4[ib];
        float4 lo, hi;
        lo.x = fminf(va.x, vb.x); hi.x = fmaxf(va.x, vb.x);
        lo.y = fminf(va.y, vb.y); hi.y = fmaxf(va.y, vb.y);
        lo.z = fminf(va.z, vb.z); hi.z = fmaxf(va.z, vb.z);
        lo.w = fminf(va.w, vb.w); hi.w = fmaxf(va.w, vb.w);
        S4[ia] = desc ? hi : lo;
        S4[ib] = desc ? lo : hi;
      }
      __syncthreads();
    }
    // register pass: j = 16,8,4,2,1 within each 32-chunk
#pragma unroll
    for (int c = 0; c < 2; ++c) {
      const int cid = tid + (c << 8);
      const int row = cid >> 5;
      const int chunk = cid & 31;
      const bool D = (((chunk << 5) & k) == 0);
      float r[32];
#pragma unroll
      for (int q = 0; q < 8; ++q) {
        float4 t = S4[sw4(row, (chunk << 3) + q)];
        r[q * 4 + 0] = t.x; r[q * 4 + 1] = t.y; r[q * 4 + 2] = t.z; r[q * 4 + 3] = t.w;
      }
#pragma unroll
      for (int j = 16; j > 0; j >>= 1) {
#pragma unroll
        for (int i = 0; i < 32; ++i) {
          if ((i & j) == 0) ce(r[i], r[i | j], D);
        }
      }
#pragma unroll
      for (int q = 0; q < 8; ++q) {
        S4[sw4(row, (chunk << 3) + q)] =
            make_float4(r[q * 4 + 0], r[q * 4 + 1], r[q * 4 + 2], r[q * 4 + 3]);
      }
    }
    __syncthreads();
  }

  // ---- gather ranks and store (coalesced along p) ----
  const int p = tid;
  const int rank = (int)rint(1.0 + (double)p * (1022.0 / 255.0));
#pragma unroll
  for (int m = 0; m < TM; ++m) {
    out[((size_t)(b * NMAPS + m0 + m) << 8) + p] = lds[sw4(m, rank >> 2) * 4 + (rank & 3)];
  }
}

extern "C" void kernel_launch(void* const* d_in, const int* in_sizes, int n_in,
                              void* d_out, int out_size, void* d_ws, size_t ws_size,
                              hipStream_t stream) {
  const float* x = reinterpret_cast<const float*>(d_in[0]);
  float* out = reinterpret_cast<float*>(d_out);
  const int B = in_sizes[0] / (NMAPS * FDIM);  // 32
  dim3 grid(NMAPS / TM, B);
  hipLaunchKernelGGL(selfcorr_pool_kernel, grid, dim3(NT), 0, stream, x, out);
}

// Round 2
// 686.351 us; speedup vs baseline: 2.0285x; 2.0285x over previous
//
#include <hip/hip_runtime.h>

// SelfCorrelationPercPooling: x (32,32,32,512) f32 ->
//   corr[b] = X·Xᵀ/512 (1024x1024), per-row descending sort, gather 256 ranks.
// v2: bf16 MFMA GEMM (fragments straight from L2-resident bf16 copy of x in d_ws),
//     sort unchanged from v1 (verified). Fallback to v1 fp32 kernel if ws too small.

#define NMAPS 1024
#define FDIM 512
#define NPOOL 256
#define TM 16
#define NT 256

typedef __attribute__((ext_vector_type(8))) short short8_t;  // bf16x8 MFMA frag
typedef __attribute__((ext_vector_type(4))) float f32x4;

// XOR swizzle on float4 index within a 1024-float row (breaks 128B-stride conflicts).
__device__ __forceinline__ int sw4(int row, int c4) {
  return (row << 8) | (c4 ^ ((c4 >> 3) & 7));
}

__device__ __forceinline__ void ce(float& a, float& b, bool desc) {
  float mn = fminf(a, b);
  float mx = fmaxf(a, b);
  a = desc ? mx : mn;
  b = desc ? mn : mx;
}

// ---------------- fp32 -> bf16 (RNE) conversion pre-pass ----------------
__global__ __launch_bounds__(256) void cvt_bf16_kernel(const float* __restrict__ x,
                                                       short* __restrict__ xw, int n8) {
  int i = blockIdx.x * 256 + threadIdx.x;
  if (i >= n8) return;
  const float4* x4 = reinterpret_cast<const float4*>(x);
  float4 a = x4[i * 2], c = x4[i * 2 + 1];
  float f[8] = {a.x, a.y, a.z, a.w, c.x, c.y, c.z, c.w};
  union { short8_t v; short s[8]; } o;
#pragma unroll
  for (int j = 0; j < 8; ++j) {
    unsigned u = __float_as_uint(f[j]);
    u += 0x7fffu + ((u >> 16) & 1u);  // round-to-nearest-even (no NaN in data)
    o.s[j] = (short)(u >> 16);
  }
  reinterpret_cast<short8_t*>(xw)[i] = o.v;
}

// ---------------- main fused kernel: MFMA GEMM + bitonic sort + rank gather ----------------
__global__ __launch_bounds__(NT) void selfcorr_mfma_kernel(const short* __restrict__ xw,
                                                           float* __restrict__ out) {
  __shared__ float lds[TM * NMAPS];  // 64 KB score buffer
  float4* S4 = reinterpret_cast<float4*>(lds);
  const int tid = threadIdx.x;
  const int b = blockIdx.y;
  const int m0 = blockIdx.x * TM;
  const int lane = tid & 63;
  const int w = tid >> 6;        // wave 0..3
  const int lr = lane & 15;      // row/col within fragment
  const int kg = lane >> 4;      // k-group 0..3
  const int wc = w * 256;        // wave's column base
  const short* Xb = xw + (size_t)b * NMAPS * FDIM;  // row-major [1024][512] bf16

  // ---- GEMM: acc[t] = 16x16 tile at (m0.., wc + 16t..), K=512 in 16 steps ----
  f32x4 acc[16];
#pragma unroll
  for (int t = 0; t < 16; ++t) acc[t] = (f32x4){0.f, 0.f, 0.f, 0.f};

  for (int kk = 0; kk < 16; ++kk) {
    // fragment base: k offset kk*32 + kg*8 (16B aligned); row stride = 64 short8
    const short8_t* base = reinterpret_cast<const short8_t*>(Xb + kk * 32 + kg * 8);
    short8_t afrag = base[(size_t)(m0 + lr) * 64];
    short8_t bfrag[16];
#pragma unroll
    for (int t = 0; t < 16; ++t) bfrag[t] = base[(size_t)(wc + t * 16 + lr) * 64];
#pragma unroll
    for (int t = 0; t < 16; ++t)
      acc[t] = __builtin_amdgcn_mfma_f32_16x16x32_bf16(afrag, bfrag[t], acc[t], 0, 0, 0);
  }

  // ---- dump accumulators to swizzled LDS scores, scaled 1/F ----
  // C/D layout: col = lane&15, row = (lane>>4)*4 + reg  [verified m89]
#pragma unroll
  for (int t = 0; t < 16; ++t) {
#pragma unroll
    for (int reg = 0; reg < 4; ++reg) {
      const int r = kg * 4 + reg;
      const int c = wc + t * 16 + lr;
      lds[sw4(r, c >> 2) * 4 + (c & 3)] = acc[t][reg] * (1.0f / FDIM);
    }
  }
  __syncthreads();

  // ---- sort phase 1: each thread fully sorts two 32-chunks in registers ----
#pragma unroll
  for (int c = 0; c < 2; ++c) {
    const int cid = tid + (c << 8);
    const int row = cid >> 5;
    const int chunk = cid & 31;
    float r[32];
#pragma unroll
    for (int q = 0; q < 8; ++q) {
      float4 t = S4[sw4(row, (chunk << 3) + q)];
      r[q * 4 + 0] = t.x; r[q * 4 + 1] = t.y; r[q * 4 + 2] = t.z; r[q * 4 + 3] = t.w;
    }
    const bool D = ((chunk & 1) == 0);
#pragma unroll
    for (int k2 = 2; k2 <= 32; k2 <<= 1) {
#pragma unroll
      for (int j = k2 >> 1; j > 0; j >>= 1) {
#pragma unroll
        for (int i = 0; i < 32; ++i) {
          if ((i & j) == 0) ce(r[i], r[i | j], ((i & k2) == 0) ? D : !D);
        }
      }
    }
#pragma unroll
    for (int q = 0; q < 8; ++q) {
      S4[sw4(row, (chunk << 3) + q)] =
          make_float4(r[q * 4 + 0], r[q * 4 + 1], r[q * 4 + 2], r[q * 4 + 3]);
    }
  }
  __syncthreads();

  // ---- sort phase 2: merges k = 64..1024 ----
  for (int k = 64; k <= NMAPS; k <<= 1) {
    for (int j = k >> 1; j >= 32; j >>= 1) {
      const int j4 = j >> 2;
      const int kq = k >> 2;
#pragma unroll
      for (int q = 0; q < 8; ++q) {
        const int g = tid + (q << 8);
        const int row = g >> 7;
        const int v = g & 127;
        const int i4 = ((v & ~(j4 - 1)) << 1) | (v & (j4 - 1));
        const bool desc = ((i4 & kq) == 0);
        const int ia = sw4(row, i4);
        const int ib = sw4(row, i4 + j4);
        float4 va = S4[ia];
        float4 vb = S4[ib];
        float4 lo, hi;
        lo.x = fminf(va.x, vb.x); hi.x = fmaxf(va.x, vb.x);
        lo.y = fminf(va.y, vb.y); hi.y = fmaxf(va.y, vb.y);
        lo.z = fminf(va.z, vb.z); hi.z = fmaxf(va.z, vb.z);
        lo.w = fminf(va.w, vb.w); hi.w = fmaxf(va.w, vb.w);
        S4[ia] = desc ? hi : lo;
        S4[ib] = desc ? lo : hi;
      }
      __syncthreads();
    }
    // register pass: j = 16,8,4,2,1 within each 32-chunk
#pragma unroll
    for (int c = 0; c < 2; ++c) {
      const int cid = tid + (c << 8);
      const int row = cid >> 5;
      const int chunk = cid & 31;
      const bool D = (((chunk << 5) & k) == 0);
      float r[32];
#pragma unroll
      for (int q = 0; q < 8; ++q) {
        float4 t = S4[sw4(row, (chunk << 3) + q)];
        r[q * 4 + 0] = t.x; r[q * 4 + 1] = t.y; r[q * 4 + 2] = t.z; r[q * 4 + 3] = t.w;
      }
#pragma unroll
      for (int j = 16; j > 0; j >>= 1) {
#pragma unroll
        for (int i = 0; i < 32; ++i) {
          if ((i & j) == 0) ce(r[i], r[i | j], D);
        }
      }
#pragma unroll
      for (int q = 0; q < 8; ++q) {
        S4[sw4(row, (chunk << 3) + q)] =
            make_float4(r[q * 4 + 0], r[q * 4 + 1], r[q * 4 + 2], r[q * 4 + 3]);
      }
    }
    __syncthreads();
  }

  // ---- gather ranks and store (coalesced along p) ----
  const int p = tid;
  const int rank = (int)rint(1.0 + (double)p * (1022.0 / 255.0));
#pragma unroll
  for (int m = 0; m < TM; ++m) {
    out[((size_t)(b * NMAPS + m0 + m) << 8) + p] = lds[sw4(m, rank >> 2) * 4 + (rank & 3)];
  }
}

// ---------------- v1 fp32 fallback (used only if ws_size < 2*nelem bytes) ----------------
__global__ __launch_bounds__(NT) void selfcorr_pool_kernel(const float* __restrict__ x,
                                                           float* __restrict__ out) {
  __shared__ float lds[TM * NMAPS];
  float4* S4 = reinterpret_cast<float4*>(lds);
  const int tid = threadIdx.x;
  const int b = blockIdx.y;
  const int m0 = blockIdx.x * TM;
  const float4* Xb = reinterpret_cast<const float4*>(x) + (size_t)b * NMAPS * (FDIM / 4);

  float4* A4 = reinterpret_cast<float4*>(lds);
#pragma unroll
  for (int idx = tid; idx < TM * (FDIM / 4); idx += NT) {
    A4[idx] = Xb[(m0 + (idx >> 7)) * 128 + (idx & 127)];
  }
  __syncthreads();

  float acc[TM][4];
#pragma unroll
  for (int m = 0; m < TM; ++m)
#pragma unroll
    for (int j = 0; j < 4; ++j) acc[m][j] = 0.0f;

  float4 nb0 = Xb[(tid + 0) * 128];
  float4 nb1 = Xb[(tid + 256) * 128];
  float4 nb2 = Xb[(tid + 512) * 128];
  float4 nb3 = Xb[(tid + 768) * 128];
  for (int k4 = 0; k4 < 128; ++k4) {
    float4 b0 = nb0, b1 = nb1, b2 = nb2, b3 = nb3;
    const int kn = (k4 < 127) ? (k4 + 1) : 127;
    nb0 = Xb[(tid + 0) * 128 + kn];
    nb1 = Xb[(tid + 256) * 128 + kn];
    nb2 = Xb[(tid + 512) * 128 + kn];
    nb3 = Xb[(tid + 768) * 128 + kn];
#pragma unroll
    for (int m = 0; m < TM; ++m) {
      float4 a = A4[m * 128 + k4];
      acc[m][0] += a.x * b0.x + a.y * b0.y + a.z * b0.z + a.w * b0.w;
      acc[m][1] += a.x * b1.x + a.y * b1.y + a.z * b1.z + a.w * b1.w;
      acc[m][2] += a.x * b2.x + a.y * b2.y + a.z * b2.z + a.w * b2.w;
      acc[m][3] += a.x * b3.x + a.y * b3.y + a.z * b3.z + a.w * b3.w;
    }
  }
  __syncthreads();

#pragma unroll
  for (int m = 0; m < TM; ++m) {
#pragma unroll
    for (int j = 0; j < 4; ++j) {
      const int n = tid + (j << 8);
      lds[sw4(m, n >> 2) * 4 + (n & 3)] = acc[m][j] * (1.0f / FDIM);
    }
  }
  __syncthreads();

#pragma unroll
  for (int c = 0; c < 2; ++c) {
    const int cid = tid + (c << 8);
    const int row = cid >> 5;
    const int chunk = cid & 31;
    float r[32];
#pragma unroll
    for (int q = 0; q < 8; ++q) {
      float4 t = S4[sw4(row, (chunk << 3) + q)];
      r[q * 4 + 0] = t.x; r[q * 4 + 1] = t.y; r[q * 4 + 2] = t.z; r[q * 4 + 3] = t.w;
    }
    const bool D = ((chunk & 1) == 0);
#pragma unroll
    for (int k2 = 2; k2 <= 32; k2 <<= 1) {
#pragma unroll
      for (int j = k2 >> 1; j > 0; j >>= 1) {
#pragma unroll
        for (int i = 0; i < 32; ++i) {
          if ((i & j) == 0) ce(r[i], r[i | j], ((i & k2) == 0) ? D : !D);
        }
      }
    }
#pragma unroll
    for (int q = 0; q < 8; ++q) {
      S4[sw4(row, (chunk << 3) + q)] =
          make_float4(r[q * 4 + 0], r[q * 4 + 1], r[q * 4 + 2], r[q * 4 + 3]);
    }
  }
  __syncthreads();

  for (int k = 64; k <= NMAPS; k <<= 1) {
    for (int j = k >> 1; j >= 32; j >>= 1) {
      const int j4 = j >> 2;
      const int kq = k >> 2;
#pragma unroll
      for (int q = 0; q < 8; ++q) {
        const int g = tid + (q << 8);
        const int row = g >> 7;
        const int v = g & 127;
        const int i4 = ((v & ~(j4 - 1)) << 1) | (v & (j4 - 1));
        const bool desc = ((i4 & kq) == 0);
        const int ia = sw4(row, i4);
        const int ib = sw4(row, i4 + j4);
        float4 va = S4[ia];
        float4 vb = S4[ib];
        float4 lo, hi;
        lo.x = fminf(va.x, vb.x); hi.x = fmaxf(va.x, vb.x);
        lo.y = fminf(va.y, vb.y); hi.y = fmaxf(va.y, vb.y);
        lo.z = fminf(va.z, vb.z); hi.z = fmaxf(va.z, vb.z);
        lo.w = fminf(va.w, vb.w); hi.w = fmaxf(va.w, vb.w);
        S4[ia] = desc ? hi : lo;
        S4[ib] = desc ? lo : hi;
      }
      __syncthreads();
    }
#pragma unroll
    for (int c = 0; c < 2; ++c) {
      const int cid = tid + (c << 8);
      const int row = cid >> 5;
      const int chunk = cid & 31;
      const bool D = (((chunk << 5) & k) == 0);
      float r[32];
#pragma unroll
      for (int q = 0; q < 8; ++q) {
        float4 t = S4[sw4(row, (chunk << 3) + q)];
        r[q * 4 + 0] = t.x; r[q * 4 + 1] = t.y; r[q * 4 + 2] = t.z; r[q * 4 + 3] = t.w;
      }
#pragma unroll
      for (int j = 16; j > 0; j >>= 1) {
#pragma unroll
        for (int i = 0; i < 32; ++i) {
          if ((i & j) == 0) ce(r[i], r[i | j], D);
        }
      }
#pragma unroll
      for (int q = 0; q < 8; ++q) {
        S4[sw4(row, (chunk << 3) + q)] =
            make_float4(r[q * 4 + 0], r[q * 4 + 1], r[q * 4 + 2], r[q * 4 + 3]);
      }
    }
    __syncthreads();
  }

  const int p = tid;
  const int rank = (int)rint(1.0 + (double)p * (1022.0 / 255.0));
#pragma unroll
  for (int m = 0; m < TM; ++m) {
    out[((size_t)(b * NMAPS + m0 + m) << 8) + p] = lds[sw4(m, rank >> 2) * 4 + (rank & 3)];
  }
}

extern "C" void kernel_launch(void* const* d_in, const int* in_sizes, int n_in,
                              void* d_out, int out_size, void* d_ws, size_t ws_size,
                              hipStream_t stream) {
  const float* x = reinterpret_cast<const float*>(d_in[0]);
  float* out = reinterpret_cast<float*>(d_out);
  const int nelem = in_sizes[0];
  const int B = nelem / (NMAPS * FDIM);  // 32
  dim3 grid(NMAPS / TM, B);
  if (ws_size >= (size_t)nelem * 2) {
    short* xw = reinterpret_cast<short*>(d_ws);
    const int n8 = nelem / 8;
    hipLaunchKernelGGL(cvt_bf16_kernel, dim3((n8 + 255) / 256), dim3(256), 0, stream, x, xw, n8);
    hipLaunchKernelGGL(selfcorr_mfma_kernel, grid, dim3(NT), 0, stream, xw, out);
  } else {
    hipLaunchKernelGGL(selfcorr_pool_kernel, grid, dim3(NT), 0, stream, x, out);
  }
}

// Round 3
// 659.870 us; speedup vs baseline: 2.1100x; 1.0401x over previous
//
#include <hip/hip_runtime.h>

// SelfCorrelationPercPooling: x (32,32,32,512) f32 ->
//   corr[b] = X·Xᵀ/512 (1024x1024), per-row descending sort, gather 256 ranks.
// v3: bf16 MFMA GEMM (unchanged, verified) + BARRIER-FREE sort: each wave owns
//     4 rows and runs all bitonic levels wave-synchronously (DS ops from one
//     wave complete in order; only compiler fences needed). One __syncthreads
//     total (after the accumulator dump).

#define NMAPS 1024
#define FDIM 512
#define NPOOL 256
#define TM 16
#define NT 256

typedef __attribute__((ext_vector_type(8))) short short8_t;  // bf16x8 MFMA frag
typedef __attribute__((ext_vector_type(4))) float f32x4;

// XOR swizzle on float4 index within a 1024-float row (breaks 128B-stride conflicts).
__device__ __forceinline__ int sw4(int row, int c4) {
  return (row << 8) | (c4 ^ ((c4 >> 3) & 7));
}

__device__ __forceinline__ void ce(float& a, float& b, bool desc) {
  float mn = fminf(a, b);
  float mx = fmaxf(a, b);
  a = desc ? mx : mn;
  b = desc ? mn : mx;
}

// Wave-level fence: no hardware cost; stops the compiler from moving LDS ops
// across sort levels. Same-wave DS ops execute in program order in HW.
__device__ __forceinline__ void wave_fence() {
  __builtin_amdgcn_wave_barrier();
}

// ---------------- fp32 -> bf16 (RNE) conversion pre-pass ----------------
__global__ __launch_bounds__(256) void cvt_bf16_kernel(const float* __restrict__ x,
                                                       short* __restrict__ xw, int n8) {
  int i = blockIdx.x * 256 + threadIdx.x;
  if (i >= n8) return;
  const float4* x4 = reinterpret_cast<const float4*>(x);
  float4 a = x4[i * 2], c = x4[i * 2 + 1];
  float f[8] = {a.x, a.y, a.z, a.w, c.x, c.y, c.z, c.w};
  union { short8_t v; short s[8]; } o;
#pragma unroll
  for (int j = 0; j < 8; ++j) {
    unsigned u = __float_as_uint(f[j]);
    u += 0x7fffu + ((u >> 16) & 1u);  // round-to-nearest-even (no NaN in data)
    o.s[j] = (short)(u >> 16);
  }
  reinterpret_cast<short8_t*>(xw)[i] = o.v;
}

// ---------------- main fused kernel: MFMA GEMM + wave-local bitonic sort ----------------
__global__ __launch_bounds__(NT) void selfcorr_mfma_kernel(const short* __restrict__ xw,
                                                           float* __restrict__ out) {
  __shared__ float lds[TM * NMAPS];  // 64 KB score buffer
  float4* S4 = reinterpret_cast<float4*>(lds);
  const int tid = threadIdx.x;
  const int b = blockIdx.y;
  const int m0 = blockIdx.x * TM;
  const int lane = tid & 63;
  const int w = tid >> 6;        // wave 0..3
  const int lr = lane & 15;      // row/col within fragment
  const int kg = lane >> 4;      // k-group 0..3
  const int wc = w * 256;        // wave's column base (GEMM)
  const short* Xb = xw + (size_t)b * NMAPS * FDIM;  // row-major [1024][512] bf16

  // ---- GEMM: acc[t] = 16x16 tile at (m0.., wc + 16t..), K=512 in 16 steps ----
  f32x4 acc[16];
#pragma unroll
  for (int t = 0; t < 16; ++t) acc[t] = (f32x4){0.f, 0.f, 0.f, 0.f};

  for (int kk = 0; kk < 16; ++kk) {
    const short8_t* base = reinterpret_cast<const short8_t*>(Xb + kk * 32 + kg * 8);
    short8_t afrag = base[(size_t)(m0 + lr) * 64];
    short8_t bfrag[16];
#pragma unroll
    for (int t = 0; t < 16; ++t) bfrag[t] = base[(size_t)(wc + t * 16 + lr) * 64];
#pragma unroll
    for (int t = 0; t < 16; ++t)
      acc[t] = __builtin_amdgcn_mfma_f32_16x16x32_bf16(afrag, bfrag[t], acc[t], 0, 0, 0);
  }

  // ---- dump accumulators to swizzled LDS scores, scaled 1/F ----
  // C/D layout: col = lane&15, row = (lane>>4)*4 + reg
#pragma unroll
  for (int t = 0; t < 16; ++t) {
#pragma unroll
    for (int reg = 0; reg < 4; ++reg) {
      const int r = kg * 4 + reg;
      const int c = wc + t * 16 + lr;
      lds[sw4(r, c >> 2) * 4 + (c & 3)] = acc[t][reg] * (1.0f / FDIM);
    }
  }
  __syncthreads();  // the ONLY workgroup barrier: rows were written by all waves

  // ================= wave-local sort: wave w owns rows rowbase..rowbase+3 =================
  const int rowbase = w * 4;

  // ---- phase 1: 128 chunks (4 rows x 32 chunks); each lane fully sorts 2 chunks ----
#pragma unroll
  for (int c = 0; c < 2; ++c) {
    const int cid = lane + (c << 6);          // 0..127
    const int row = rowbase + (cid >> 5);
    const int chunk = cid & 31;
    float r[32];
#pragma unroll
    for (int q = 0; q < 8; ++q) {
      float4 t = S4[sw4(row, (chunk << 3) + q)];
      r[q * 4 + 0] = t.x; r[q * 4 + 1] = t.y; r[q * 4 + 2] = t.z; r[q * 4 + 3] = t.w;
    }
    const bool D = ((chunk & 1) == 0);
#pragma unroll
    for (int k2 = 2; k2 <= 32; k2 <<= 1) {
#pragma unroll
      for (int j = k2 >> 1; j > 0; j >>= 1) {
#pragma unroll
        for (int i = 0; i < 32; ++i) {
          if ((i & j) == 0) ce(r[i], r[i | j], ((i & k2) == 0) ? D : !D);
        }
      }
    }
#pragma unroll
    for (int q = 0; q < 8; ++q) {
      S4[sw4(row, (chunk << 3) + q)] =
          make_float4(r[q * 4 + 0], r[q * 4 + 1], r[q * 4 + 2], r[q * 4 + 3]);
    }
  }
  wave_fence();

  // ---- phase 2: merges k = 64..1024, all wave-local ----
  for (int k = 64; k <= NMAPS; k <<= 1) {
    for (int j = k >> 1; j >= 32; j >>= 1) {
      const int j4 = j >> 2;
      const int kq = k >> 2;
#pragma unroll
      for (int q = 0; q < 8; ++q) {
        const int g = lane + (q << 6);        // 0..511: 128 vec-CE per row per level
        const int row = rowbase + (g >> 7);
        const int v = g & 127;
        const int i4 = ((v & ~(j4 - 1)) << 1) | (v & (j4 - 1));
        const bool desc = ((i4 & kq) == 0);
        const int ia = sw4(row, i4);
        const int ib = sw4(row, i4 + j4);
        float4 va = S4[ia];
        float4 vb = S4[ib];
        float4 lo, hi;
        lo.x = fminf(va.x, vb.x); hi.x = fmaxf(va.x, vb.x);
        lo.y = fminf(va.y, vb.y); hi.y = fmaxf(va.y, vb.y);
        lo.z = fminf(va.z, vb.z); hi.z = fmaxf(va.z, vb.z);
        lo.w = fminf(va.w, vb.w); hi.w = fmaxf(va.w, vb.w);
        S4[ia] = desc ? hi : lo;
        S4[ib] = desc ? lo : hi;
      }
      wave_fence();
    }
    // register pass: j = 16,8,4,2,1 within each 32-chunk
#pragma unroll
    for (int c = 0; c < 2; ++c) {
      const int cid = lane + (c << 6);
      const int row = rowbase + (cid >> 5);
      const int chunk = cid & 31;
      const bool D = (((chunk << 5) & k) == 0);
      float r[32];
#pragma unroll
      for (int q = 0; q < 8; ++q) {
        float4 t = S4[sw4(row, (chunk << 3) + q)];
        r[q * 4 + 0] = t.x; r[q * 4 + 1] = t.y; r[q * 4 + 2] = t.z; r[q * 4 + 3] = t.w;
      }
#pragma unroll
      for (int j = 16; j > 0; j >>= 1) {
#pragma unroll
        for (int i = 0; i < 32; ++i) {
          if ((i & j) == 0) ce(r[i], r[i | j], D);
        }
      }
#pragma unroll
      for (int q = 0; q < 8; ++q) {
        S4[sw4(row, (chunk << 3) + q)] =
            make_float4(r[q * 4 + 0], r[q * 4 + 1], r[q * 4 + 2], r[q * 4 + 3]);
      }
    }
    wave_fence();
  }

  // ---- gather ranks and store (coalesced along p), wave-local rows ----
#pragma unroll
  for (int i = 0; i < 16; ++i) {
    const int row = rowbase + (i >> 2);
    const int p = lane + ((i & 3) << 6);
    const int rank = (int)rint(1.0 + (double)p * (1022.0 / 255.0));
    out[((size_t)(b * NMAPS + m0 + row) << 8) + p] = lds[sw4(row, rank >> 2) * 4 + (rank & 3)];
  }
}

// ---------------- v1 fp32 fallback (used only if ws_size < 2*nelem bytes) ----------------
__global__ __launch_bounds__(NT) void selfcorr_pool_kernel(const float* __restrict__ x,
                                                           float* __restrict__ out) {
  __shared__ float lds[TM * NMAPS];
  float4* S4 = reinterpret_cast<float4*>(lds);
  const int tid = threadIdx.x;
  const int b = blockIdx.y;
  const int m0 = blockIdx.x * TM;
  const float4* Xb = reinterpret_cast<const float4*>(x) + (size_t)b * NMAPS * (FDIM / 4);

  float4* A4 = reinterpret_cast<float4*>(lds);
#pragma unroll
  for (int idx = tid; idx < TM * (FDIM / 4); idx += NT) {
    A4[idx] = Xb[(m0 + (idx >> 7)) * 128 + (idx & 127)];
  }
  __syncthreads();

  float acc[TM][4];
#pragma unroll
  for (int m = 0; m < TM; ++m)
#pragma unroll
    for (int j = 0; j < 4; ++j) acc[m][j] = 0.0f;

  float4 nb0 = Xb[(tid + 0) * 128];
  float4 nb1 = Xb[(tid + 256) * 128];
  float4 nb2 = Xb[(tid + 512) * 128];
  float4 nb3 = Xb[(tid + 768) * 128];
  for (int k4 = 0; k4 < 128; ++k4) {
    float4 b0 = nb0, b1 = nb1, b2 = nb2, b3 = nb3;
    const int kn = (k4 < 127) ? (k4 + 1) : 127;
    nb0 = Xb[(tid + 0) * 128 + kn];
    nb1 = Xb[(tid + 256) * 128 + kn];
    nb2 = Xb[(tid + 512) * 128 + kn];
    nb3 = Xb[(tid + 768) * 128 + kn];
#pragma unroll
    for (int m = 0; m < TM; ++m) {
      float4 a = A4[m * 128 + k4];
      acc[m][0] += a.x * b0.x + a.y * b0.y + a.z * b0.z + a.w * b0.w;
      acc[m][1] += a.x * b1.x + a.y * b1.y + a.z * b1.z + a.w * b1.w;
      acc[m][2] += a.x * b2.x + a.y * b2.y + a.z * b2.z + a.w * b2.w;
      acc[m][3] += a.x * b3.x + a.y * b3.y + a.z * b3.z + a.w * b3.w;
    }
  }
  __syncthreads();

#pragma unroll
  for (int m = 0; m < TM; ++m) {
#pragma unroll
    for (int j = 0; j < 4; ++j) {
      const int n = tid + (j << 8);
      lds[sw4(m, n >> 2) * 4 + (n & 3)] = acc[m][j] * (1.0f / FDIM);
    }
  }
  __syncthreads();

#pragma unroll
  for (int c = 0; c < 2; ++c) {
    const int cid = tid + (c << 8);
    const int row = cid >> 5;
    const int chunk = cid & 31;
    float r[32];
#pragma unroll
    for (int q = 0; q < 8; ++q) {
      float4 t = S4[sw4(row, (chunk << 3) + q)];
      r[q * 4 + 0] = t.x; r[q * 4 + 1] = t.y; r[q * 4 + 2] = t.z; r[q * 4 + 3] = t.w;
    }
    const bool D = ((chunk & 1) == 0);
#pragma unroll
    for (int k2 = 2; k2 <= 32; k2 <<= 1) {
#pragma unroll
      for (int j = k2 >> 1; j > 0; j >>= 1) {
#pragma unroll
        for (int i = 0; i < 32; ++i) {
          if ((i & j) == 0) ce(r[i], r[i | j], ((i & k2) == 0) ? D : !D);
        }
      }
    }
#pragma unroll
    for (int q = 0; q < 8; ++q) {
      S4[sw4(row, (chunk << 3) + q)] =
          make_float4(r[q * 4 + 0], r[q * 4 + 1], r[q * 4 + 2], r[q * 4 + 3]);
    }
  }
  __syncthreads();

  for (int k = 64; k <= NMAPS; k <<= 1) {
    for (int j = k >> 1; j >= 32; j >>= 1) {
      const int j4 = j >> 2;
      const int kq = k >> 2;
#pragma unroll
      for (int q = 0; q < 8; ++q) {
        const int g = tid + (q << 8);
        const int row = g >> 7;
        const int v = g & 127;
        const int i4 = ((v & ~(j4 - 1)) << 1) | (v & (j4 - 1));
        const bool desc = ((i4 & kq) == 0);
        const int ia = sw4(row, i4);
        const int ib = sw4(row, i4 + j4);
        float4 va = S4[ia];
        float4 vb = S4[ib];
        float4 lo, hi;
        lo.x = fminf(va.x, vb.x); hi.x = fmaxf(va.x, vb.x);
        lo.y = fminf(va.y, vb.y); hi.y = fmaxf(va.y, vb.y);
        lo.z = fminf(va.z, vb.z); hi.z = fmaxf(va.z, vb.z);
        lo.w = fminf(va.w, vb.w); hi.w = fmaxf(va.w, vb.w);
        S4[ia] = desc ? hi : lo;
        S4[ib] = desc ? lo : hi;
      }
      __syncthreads();
    }
#pragma unroll
    for (int c = 0; c < 2; ++c) {
      const int cid = tid + (c << 8);
      const int row = cid >> 5;
      const int chunk = cid & 31;
      const bool D = (((chunk << 5) & k) == 0);
      float r[32];
#pragma unroll
      for (int q = 0; q < 8; ++q) {
        float4 t = S4[sw4(row, (chunk << 3) + q)];
        r[q * 4 + 0] = t.x; r[q * 4 + 1] = t.y; r[q * 4 + 2] = t.z; r[q * 4 + 3] = t.w;
      }
#pragma unroll
      for (int j = 16; j > 0; j >>= 1) {
#pragma unroll
        for (int i = 0; i < 32; ++i) {
          if ((i & j) == 0) ce(r[i], r[i | j], D);
        }
      }
#pragma unroll
      for (int q = 0; q < 8; ++q) {
        S4[sw4(row, (chunk << 3) + q)] =
            make_float4(r[q * 4 + 0], r[q * 4 + 1], r[q * 4 + 2], r[q * 4 + 3]);
      }
    }
    __syncthreads();
  }

  const int p = tid;
  const int rank = (int)rint(1.0 + (double)p * (1022.0 / 255.0));
#pragma unroll
  for (int m = 0; m < TM; ++m) {
    out[((size_t)(b * NMAPS + m0 + m) << 8) + p] = lds[sw4(m, rank >> 2) * 4 + (rank & 3)];
  }
}

extern "C" void kernel_launch(void* const* d_in, const int* in_sizes, int n_in,
                              void* d_out, int out_size, void* d_ws, size_t ws_size,
                              hipStream_t stream) {
  const float* x = reinterpret_cast<const float*>(d_in[0]);
  float* out = reinterpret_cast<float*>(d_out);
  const int nelem = in_sizes[0];
  const int B = nelem / (NMAPS * FDIM);  // 32
  dim3 grid(NMAPS / TM, B);
  if (ws_size >= (size_t)nelem * 2) {
    short* xw = reinterpret_cast<short*>(d_ws);
    const int n8 = nelem / 8;
    hipLaunchKernelGGL(cvt_bf16_kernel, dim3((n8 + 255) / 256), dim3(256), 0, stream, x, xw, n8);
    hipLaunchKernelGGL(selfcorr_mfma_kernel, grid, dim3(NT), 0, stream, xw, out);
  } else {
    hipLaunchKernelGGL(selfcorr_pool_kernel, grid, dim3(NT), 0, stream, x, out);
  }
}

// Round 5
// 282.795 us; speedup vs baseline: 4.9233x; 2.3334x over previous
//
#include <hip/hip_runtime.h>

// SelfCorrelationPercPooling: x (32,32,32,512) f32 ->
//   corr[b] = X·Xᵀ/512 (1024x1024), per-row descending sort, gather 256 ranks.
// v5 (= v4 with native _Float16 vectors): bf16 MFMA GEMM with SWAPPED operands
//   (lane owns one corr-row, 4 consecutive cols per acc reg pair) -> packed fp16
//   dump to 32KB LDS (occupancy 2->4/5 blocks/CU) -> full-register wave bitonic
//   sort (v_pk_min/max_f16 + shfl_xor) -> rank gather. One __syncthreads total.

#define NMAPS 1024
#define FDIM 512
#define TM 16
#define NT 256

typedef __attribute__((ext_vector_type(8))) short short8_t;  // bf16x8 MFMA frag
typedef __attribute__((ext_vector_type(4))) float f32x4;
typedef _Float16 h2 __attribute__((ext_vector_type(2)));     // packed fp16 pair

__device__ __forceinline__ h2 h2min(h2 a, h2 b) { return __builtin_elementwise_min(a, b); }
__device__ __forceinline__ h2 h2max(h2 a, h2 b) { return __builtin_elementwise_max(a, b); }

__device__ __forceinline__ h2 h2swap(h2 v) {  // swap low/high halves
  union { h2 h; unsigned u; } x;
  x.h = v;
  x.u = (x.u >> 16) | (x.u << 16);
  return x.h;
}

__device__ __forceinline__ h2 h2shfl_xor(h2 v, int m) {
  union { h2 h; int i; } u;
  u.h = v;
  u.i = __shfl_xor(u.i, m, 64);
  return u.h;
}

// One bitonic stage (block size K) on 1024 elements held as 8 h2/lane.
// Element i = lane*16 + 2*u + h. Direction: desc = ((i & K) == 0); final
// stage K=1024 -> descending everywhere.
template<int K>
__device__ __forceinline__ void bitonic_stage(h2 w8[8], int lane) {
  const bool laneDesc = (K >= 16) ? ((lane & (K >> 4)) == 0) : true;
#pragma unroll
  for (int j = 512; j >= 16; j >>= 1) {
    if (j > (K >> 1)) continue;               // compile-time prune
    const int m = j >> 4;                     // lane xor mask (1..32)
    const bool keepmax = (((lane & m) == 0) == laneDesc);
#pragma unroll
    for (int u = 0; u < 8; ++u) {
      h2 p = h2shfl_xor(w8[u], m);
      h2 mn = h2min(w8[u], p), mx = h2max(w8[u], p);
      w8[u] = keepmax ? mx : mn;
    }
  }
#pragma unroll
  for (int j = 8; j >= 2; j >>= 1) {
    if (j > (K >> 1)) continue;
    const int jw = j >> 1;                    // word-pair stride
#pragma unroll
    for (int u = 0; u < 8; ++u) {
      if ((u & jw) == 0) {
        const int v = u | jw;
        const bool desc = (K <= 8) ? (((2 * u) & K) == 0) : laneDesc;
        h2 mn = h2min(w8[u], w8[v]), mx = h2max(w8[u], w8[v]);
        w8[u] = desc ? mx : mn;
        w8[v] = desc ? mn : mx;
      }
    }
  }
  // j == 1: compare-exchange the two halves of each word
#pragma unroll
  for (int u = 0; u < 8; ++u) {
    const bool desc = (K <= 8) ? (((2 * u) & K) == 0) : laneDesc;
    h2 s = h2swap(w8[u]);
    h2 mn = h2min(w8[u], s), mx = h2max(w8[u], s);  // mn/mx: both lanes = overall min/max
    h2 rd = (h2){mx[0], mn[1]};  // desc: (max, min)
    h2 ra = (h2){mn[0], mx[1]};  // asc:  (min, max)
    w8[u] = desc ? rd : ra;
  }
}

// ---------------- fp32 -> bf16 (RNE) conversion pre-pass ----------------
__global__ __launch_bounds__(256) void cvt_bf16_kernel(const float* __restrict__ x,
                                                       short* __restrict__ xw, int n8) {
  int i = blockIdx.x * 256 + threadIdx.x;
  if (i >= n8) return;
  const float4* x4 = reinterpret_cast<const float4*>(x);
  float4 a = x4[i * 2], c = x4[i * 2 + 1];
  float f[8] = {a.x, a.y, a.z, a.w, c.x, c.y, c.z, c.w};
  union { short8_t v; short s[8]; } o;
#pragma unroll
  for (int j = 0; j < 8; ++j) {
    unsigned u = __float_as_uint(f[j]);
    u += 0x7fffu + ((u >> 16) & 1u);  // RNE (no NaN in data)
    o.s[j] = (short)(u >> 16);
  }
  reinterpret_cast<short8_t*>(xw)[i] = o.v;
}

// ---------------- main fused kernel ----------------
__global__ __launch_bounds__(NT) void selfcorr_mfma_kernel(const short* __restrict__ xw,
                                                           float* __restrict__ out) {
  __shared__ alignas(16) h2 SH[TM * 512];  // 32 KB: [16 rows][512 h2 words]
  const int tid = threadIdx.x;
  const int b = blockIdx.y;
  const int m0 = blockIdx.x * TM;
  const int lane = tid & 63;
  const int wid = tid >> 6;      // wave 0..3
  const int lr = lane & 15;
  const int kg = lane >> 4;      // 0..3
  const int wc = wid * 256;      // wave's column base
  const short* Xb = xw + (size_t)b * NMAPS * FDIM;  // [1024][512] bf16

  // ---- GEMM, operands SWAPPED: value(lane,reg,t) = corr[m0+lr][wc + t*16 + kg*4 + reg]
  f32x4 acc[16];
#pragma unroll
  for (int t = 0; t < 16; ++t) acc[t] = (f32x4){0.f, 0.f, 0.f, 0.f};

  for (int kk = 0; kk < 16; ++kk) {
    const short8_t* base = reinterpret_cast<const short8_t*>(Xb + kk * 32 + kg * 8);
    short8_t afrag = base[(size_t)(m0 + lr) * 64];
    short8_t bfrag[16];
#pragma unroll
    for (int t = 0; t < 16; ++t) bfrag[t] = base[(size_t)(wc + t * 16 + lr) * 64];
#pragma unroll
    for (int t = 0; t < 16; ++t)
      acc[t] = __builtin_amdgcn_mfma_f32_16x16x32_bf16(bfrag[t], afrag, acc[t], 0, 0, 0);
  }

  // ---- dump: lane owns row lr; per t, 4 consecutive cols -> 2 h2 words -> 8B write
  // LDS word swizzle: phys(row, W) = row*512 + (W ^ ((row&7)<<2))  (b64/b128-safe)
  {
    const int xorv = (lr & 7) << 2;
#pragma unroll
    for (int t = 0; t < 16; ++t) {
      h2 lo = (h2){(_Float16)(acc[t][0] * (1.f / FDIM)), (_Float16)(acc[t][1] * (1.f / FDIM))};
      h2 hi = (h2){(_Float16)(acc[t][2] * (1.f / FDIM)), (_Float16)(acc[t][3] * (1.f / FDIM))};
      const int W = (wc >> 1) + t * 8 + kg * 2;     // even word index in row
      const int phys = lr * 512 + (W ^ xorv);
      union { h2 h[2]; uint2 u; } pk;
      pk.h[0] = lo; pk.h[1] = hi;
      *reinterpret_cast<uint2*>(&SH[phys]) = pk.u;  // 8B aligned (phys even)
    }
  }
  __syncthreads();  // all waves wrote pieces of every row

  // ---- wave-register sort: wave sorts rows rowbase..rowbase+3, one at a time
  const int rowbase = wid * 4;
  for (int rr = rowbase; rr < rowbase + 4; ++rr) {
    const int rx = (rr & 7) << 2;
    h2 w8[8];  // elements i = lane*16 + 2u + h
#pragma unroll
    for (int q = 0; q < 2; ++q) {
      const int p4 = rr * 512 + ((lane * 8 + q * 4) ^ rx);
      union { uint4 u; h2 h[4]; } un;
      un.u = *reinterpret_cast<const uint4*>(&SH[p4]);
      w8[q * 4 + 0] = un.h[0]; w8[q * 4 + 1] = un.h[1];
      w8[q * 4 + 2] = un.h[2]; w8[q * 4 + 3] = un.h[3];
    }
    bitonic_stage<2>(w8, lane);
    bitonic_stage<4>(w8, lane);
    bitonic_stage<8>(w8, lane);
    bitonic_stage<16>(w8, lane);
    bitonic_stage<32>(w8, lane);
    bitonic_stage<64>(w8, lane);
    bitonic_stage<128>(w8, lane);
    bitonic_stage<256>(w8, lane);
    bitonic_stage<512>(w8, lane);
    bitonic_stage<1024>(w8, lane);
#pragma unroll
    for (int q = 0; q < 2; ++q) {
      const int p4 = rr * 512 + ((lane * 8 + q * 4) ^ rx);
      union { uint4 u; h2 h[4]; } un;
      un.h[0] = w8[q * 4 + 0]; un.h[1] = w8[q * 4 + 1];
      un.h[2] = w8[q * 4 + 2]; un.h[3] = w8[q * 4 + 3];
      *reinterpret_cast<uint4*>(&SH[p4]) = un.u;
    }
  }
  __builtin_amdgcn_wave_barrier();  // order write-back vs gather (same wave, same rows)

  // ---- gather ranks (rows sorted by this wave) and store coalesced
#pragma unroll
  for (int i = 0; i < 16; ++i) {
    const int rr = rowbase + (i >> 2);
    const int p = lane + ((i & 3) << 6);
    const int rank = (int)rint(1.0 + (double)p * (1022.0 / 255.0));
    const int Wr = (rank >> 1) ^ ((rr & 7) << 2);
    h2 hv = SH[rr * 512 + Wr];
    out[((size_t)(b * NMAPS + m0 + rr) << 8) + p] = (float)hv[rank & 1];
  }
}

// ---------------- v1 fp32 fallback (only if ws_size too small) ----------------
__device__ __forceinline__ int sw4(int row, int c4) {
  return (row << 8) | (c4 ^ ((c4 >> 3) & 7));
}
__device__ __forceinline__ void ce(float& a, float& b, bool desc) {
  float mn = fminf(a, b);
  float mx = fmaxf(a, b);
  a = desc ? mx : mn;
  b = desc ? mn : mx;
}

__global__ __launch_bounds__(NT) void selfcorr_pool_kernel(const float* __restrict__ x,
                                                           float* __restrict__ out) {
  __shared__ float lds[TM * NMAPS];
  float4* S4 = reinterpret_cast<float4*>(lds);
  const int tid = threadIdx.x;
  const int b = blockIdx.y;
  const int m0 = blockIdx.x * TM;
  const float4* Xb = reinterpret_cast<const float4*>(x) + (size_t)b * NMAPS * (FDIM / 4);

  float4* A4 = reinterpret_cast<float4*>(lds);
#pragma unroll
  for (int idx = tid; idx < TM * (FDIM / 4); idx += NT) {
    A4[idx] = Xb[(m0 + (idx >> 7)) * 128 + (idx & 127)];
  }
  __syncthreads();

  float acc[TM][4];
#pragma unroll
  for (int m = 0; m < TM; ++m)
#pragma unroll
    for (int j = 0; j < 4; ++j) acc[m][j] = 0.0f;

  float4 nb0 = Xb[(tid + 0) * 128];
  float4 nb1 = Xb[(tid + 256) * 128];
  float4 nb2 = Xb[(tid + 512) * 128];
  float4 nb3 = Xb[(tid + 768) * 128];
  for (int k4 = 0; k4 < 128; ++k4) {
    float4 b0 = nb0, b1 = nb1, b2 = nb2, b3 = nb3;
    const int kn = (k4 < 127) ? (k4 + 1) : 127;
    nb0 = Xb[(tid + 0) * 128 + kn];
    nb1 = Xb[(tid + 256) * 128 + kn];
    nb2 = Xb[(tid + 512) * 128 + kn];
    nb3 = Xb[(tid + 768) * 128 + kn];
#pragma unroll
    for (int m = 0; m < TM; ++m) {
      float4 a = A4[m * 128 + k4];
      acc[m][0] += a.x * b0.x + a.y * b0.y + a.z * b0.z + a.w * b0.w;
      acc[m][1] += a.x * b1.x + a.y * b1.y + a.z * b1.z + a.w * b1.w;
      acc[m][2] += a.x * b2.x + a.y * b2.y + a.z * b2.z + a.w * b2.w;
      acc[m][3] += a.x * b3.x + a.y * b3.y + a.z * b3.z + a.w * b3.w;
    }
  }
  __syncthreads();

#pragma unroll
  for (int m = 0; m < TM; ++m) {
#pragma unroll
    for (int j = 0; j < 4; ++j) {
      const int n = tid + (j << 8);
      lds[sw4(m, n >> 2) * 4 + (n & 3)] = acc[m][j] * (1.0f / FDIM);
    }
  }
  __syncthreads();

#pragma unroll
  for (int c = 0; c < 2; ++c) {
    const int cid = tid + (c << 8);
    const int row = cid >> 5;
    const int chunk = cid & 31;
    float r[32];
#pragma unroll
    for (int q = 0; q < 8; ++q) {
      float4 t = S4[sw4(row, (chunk << 3) + q)];
      r[q * 4 + 0] = t.x; r[q * 4 + 1] = t.y; r[q * 4 + 2] = t.z; r[q * 4 + 3] = t.w;
    }
    const bool D = ((chunk & 1) == 0);
#pragma unroll
    for (int k2 = 2; k2 <= 32; k2 <<= 1) {
#pragma unroll
      for (int j = k2 >> 1; j > 0; j >>= 1) {
#pragma unroll
        for (int i = 0; i < 32; ++i) {
          if ((i & j) == 0) ce(r[i], r[i | j], ((i & k2) == 0) ? D : !D);
        }
      }
    }
#pragma unroll
    for (int q = 0; q < 8; ++q) {
      S4[sw4(row, (chunk << 3) + q)] =
          make_float4(r[q * 4 + 0], r[q * 4 + 1], r[q * 4 + 2], r[q * 4 + 3]);
    }
  }
  __syncthreads();

  for (int k = 64; k <= NMAPS; k <<= 1) {
    for (int j = k >> 1; j >= 32; j >>= 1) {
      const int j4 = j >> 2;
      const int kq = k >> 2;
#pragma unroll
      for (int q = 0; q < 8; ++q) {
        const int g = tid + (q << 8);
        const int row = g >> 7;
        const int v = g & 127;
        const int i4 = ((v & ~(j4 - 1)) << 1) | (v & (j4 - 1));
        const bool desc = ((i4 & kq) == 0);
        const int ia = sw4(row, i4);
        const int ib = sw4(row, i4 + j4);
        float4 va = S4[ia];
        float4 vb = S4[ib];
        float4 lo, hi;
        lo.x = fminf(va.x, vb.x); hi.x = fmaxf(va.x, vb.x);
        lo.y = fminf(va.y, vb.y); hi.y = fmaxf(va.y, vb.y);
        lo.z = fminf(va.z, vb.z); hi.z = fmaxf(va.z, vb.z);
        lo.w = fminf(va.w, vb.w); hi.w = fmaxf(va.w, vb.w);
        S4[ia] = desc ? hi : lo;
        S4[ib] = desc ? lo : hi;
      }
      __syncthreads();
    }
#pragma unroll
    for (int c = 0; c < 2; ++c) {
      const int cid = tid + (c << 8);
      const int row = cid >> 5;
      const int chunk = cid & 31;
      const bool D = (((chunk << 5) & k) == 0);
      float r[32];
#pragma unroll
      for (int q = 0; q < 8; ++q) {
        float4 t = S4[sw4(row, (chunk << 3) + q)];
        r[q * 4 + 0] = t.x; r[q * 4 + 1] = t.y; r[q * 4 + 2] = t.z; r[q * 4 + 3] = t.w;
      }
#pragma unroll
      for (int j = 16; j > 0; j >>= 1) {
#pragma unroll
        for (int i = 0; i < 32; ++i) {
          if ((i & j) == 0) ce(r[i], r[i | j], D);
        }
      }
#pragma unroll
      for (int q = 0; q < 8; ++q) {
        S4[sw4(row, (chunk << 3) + q)] =
            make_float4(r[q * 4 + 0], r[q * 4 + 1], r[q * 4 + 2], r[q * 4 + 3]);
      }
    }
    __syncthreads();
  }

  const int p = tid;
  const int rank = (int)rint(1.0 + (double)p * (1022.0 / 255.0));
#pragma unroll
  for (int m = 0; m < TM; ++m) {
    out[((size_t)(b * NMAPS + m0 + m) << 8) + p] = lds[sw4(m, rank >> 2) * 4 + (rank & 3)];
  }
}

extern "C" void kernel_launch(void* const* d_in, const int* in_sizes, int n_in,
                              void* d_out, int out_size, void* d_ws, size_t ws_size,
                              hipStream_t stream) {
  const float* x = reinterpret_cast<const float*>(d_in[0]);
  float* out = reinterpret_cast<float*>(d_out);
  const int nelem = in_sizes[0];
  const int B = nelem / (NMAPS * FDIM);  // 32
  dim3 grid(NMAPS / TM, B);
  if (ws_size >= (size_t)nelem * 2) {
    short* xw = reinterpret_cast<short*>(d_ws);
    const int n8 = nelem / 8;
    hipLaunchKernelGGL(cvt_bf16_kernel, dim3((n8 + 255) / 256), dim3(256), 0, stream, x, xw, n8);
    hipLaunchKernelGGL(selfcorr_mfma_kernel, grid, dim3(NT), 0, stream, xw, out);
  } else {
    hipLaunchKernelGGL(selfcorr_pool_kernel, grid, dim3(NT), 0, stream, x, out);
  }
}